// Round 20
// baseline (125.695 us; speedup 1.0000x reference)
//
#include <hip/hip_runtime.h>
#include <hip/hip_bf16.h>

typedef __hip_bfloat16 HBF;
typedef __bf16 bf16x8 __attribute__((ext_vector_type(8)));
typedef __bf16 bf16x4 __attribute__((ext_vector_type(4)));
typedef float f32x4 __attribute__((ext_vector_type(4)));
typedef float float4v __attribute__((ext_vector_type(4)));

__device__ __forceinline__ float toF(float x) { return x; }
__device__ __forceinline__ float toF(HBF x) { return __bfloat162float(x); }

#define MFMA16(a, b, c) __builtin_amdgcn_mfma_f32_16x16x32_bf16((a), (b), (c), 0, 0, 0)
#define EXP2F(x) __builtin_amdgcn_exp2f(x)
#define QSCALE 0.18033688011112042f
#define MEMFENCE asm volatile("" ::: "memory")

// async global->LDS, 16B per lane. LDS dest must be wave-uniform base; HW adds lane*16.
__device__ __forceinline__ void gload_lds16(const HBF* g, HBF* l) {
  __builtin_amdgcn_global_load_lds((const __attribute__((address_space(1))) void*)g,
                                   (__attribute__((address_space(3))) void*)l, 16, 0, 0);
}

// ---------------- fused prep: x cast + W_qkv transpose + W_proj transpose ----------------
__global__ void prep_k(const float* __restrict__ x, HBF* __restrict__ xb,
                       const float* __restrict__ Wqkv, HBF* __restrict__ wqkv_t,
                       const float* __restrict__ Wproj, HBF* __restrict__ wproj_t) {
  const int bid = blockIdx.x, tid = threadIdx.x;
  if (bid < 4096) {
    int i = bid * 256 + tid;
    float4v a = reinterpret_cast<const float4v*>(x)[i];
    HBF o[4] = {__float2bfloat16(a.x), __float2bfloat16(a.y),
                __float2bfloat16(a.z), __float2bfloat16(a.w)};
    *reinterpret_cast<ulonglong1*>(&xb[i * 4]) = *reinterpret_cast<ulonglong1*>(o);
    return;
  }
  __shared__ float tile[32][33];
  const float* in;
  HBF* out;
  int R, C, gx, gy;
  size_t base;
  if (bid < 7168) {  // W_qkv (16,1024,192) -> (16,192,1024)
    int t = bid - 4096;
    int gz = t / 192, rem = t % 192;
    gy = rem / 6; gx = rem % 6;
    R = 1024; C = 192;
    base = (size_t)gz * R * C;
    in = Wqkv; out = wqkv_t;
  } else {           // W_proj (1024,1024) -> transposed
    int t = bid - 7168;
    gy = t / 32; gx = t % 32;
    R = 1024; C = 1024;
    base = 0;
    in = Wproj; out = wproj_t;
  }
  int r0 = gy * 32, c0 = gx * 32;
  int tx = tid & 31, ty = tid >> 5;
#pragma unroll
  for (int i = ty; i < 32; i += 8)
    tile[i][tx] = in[base + (size_t)(r0 + i) * C + c0 + tx];
  __syncthreads();
#pragma unroll
  for (int i = ty; i < 32; i += 8)
    out[base + (size_t)(c0 + i) * R + r0 + tx] = __float2bfloat16(tile[tx][i]);
}

// ---------------- QKV GEMM v3 (R14 best): 128x192x64 -> 512 blocks (2/CU), counted vmcnt ----------------
__launch_bounds__(512, 4)
__global__ void gemm_qkv_8ph(const HBF* __restrict__ A, const HBF* __restrict__ Bt,
                             const float* __restrict__ bias,
                             HBF* __restrict__ Kout, HBF* __restrict__ Qout,
                             HBF* __restrict__ Vtout) {
  __shared__ __align__(16) HBF As[2][8192];
  __shared__ __align__(16) HBF Bs[2][12288];
  const int tid = threadIdx.x, lane = tid & 63, w = tid >> 6;
  const int lo = lane & 15, g4 = lane >> 4;
  const int wr = w >> 2, wc = w & 3;
  const int s = ((int)blockIdx.x & 7) * 64 + ((int)blockIdx.x >> 3);
  const int bx = s & 15, by = s >> 4;
  const int m0 = by * 128, n0 = bx * 192;  // bx == head
  const int NT = 16;  // K=1024 / 64

  f32x4 acc[4][3];
#pragma unroll
  for (int i = 0; i < 4; i++)
#pragma unroll
    for (int j = 0; j < 3; j++) acc[i][j] = (f32x4){0.f, 0.f, 0.f, 0.f};
  bf16x8 af[4][2], bfr[3][2];

  const int rl0 = w * 8 + (lane >> 3);
  const int rl1 = 64 + rl0;
  const int kc0 = (lane & 7) ^ (rl0 & 7);
  const int kc1 = (lane & 7) ^ (rl1 & 7);

  auto stageA = [&](int kt) {
    HBF* base = &As[kt & 1][0];
    gload_lds16(A + (size_t)(m0 + rl0) * 1024 + kt * 64 + kc0 * 8, base + w * 512);
    gload_lds16(A + (size_t)(m0 + rl1) * 1024 + kt * 64 + kc1 * 8, base + 4096 + w * 512);
  };
  auto stageB = [&](int kt, int g) {
    gload_lds16(Bt + (size_t)(n0 + g * 64 + rl0) * 1024 + kt * 64 + kc0 * 8,
                &Bs[kt & 1][g * 4096] + w * 512);
  };
  auto ldA = [&](int bb, int mt, int ks) -> bf16x8 {
    int row = wr * 64 + mt * 16 + lo;
    return *reinterpret_cast<const bf16x8*>(&As[bb][row * 64 + ((ks * 32 + g4 * 8) ^ ((row & 7) * 8))]);
  };
  auto ldB = [&](int bb, int nt, int ks) -> bf16x8 {
    int row = wc * 48 + nt * 16 + lo;
    return *reinterpret_cast<const bf16x8*>(&Bs[bb][row * 64 + ((ks * 32 + g4 * 8) ^ ((row & 7) * 8))]);
  };

  stageA(0); stageB(0, 0); stageB(0, 1); stageB(0, 2);
  stageA(1);
  asm volatile("s_waitcnt vmcnt(2)" ::: "memory");
  __builtin_amdgcn_s_barrier();
  MEMFENCE;

  for (int t = 0; t < NT; ++t) {
    const int bb = t & 1;
#pragma unroll
    for (int mt = 0; mt < 4; ++mt) { af[mt][0] = ldA(bb, mt, 0); af[mt][1] = ldA(bb, mt, 1); }
#pragma unroll
    for (int nt = 0; nt < 2; ++nt) { bfr[nt][0] = ldB(bb, nt, 0); bfr[nt][1] = ldB(bb, nt, 1); }
    if (t + 1 < NT) stageB(t + 1, 0);
    MEMFENCE; __builtin_amdgcn_s_barrier(); MEMFENCE;
    __builtin_amdgcn_s_setprio(1);
#pragma unroll
    for (int mt = 0; mt < 4; ++mt)
#pragma unroll
      for (int nt = 0; nt < 2; ++nt)
#pragma unroll
        for (int ks = 0; ks < 2; ++ks) acc[mt][nt] = MFMA16(af[mt][ks], bfr[nt][ks], acc[mt][nt]);
    __builtin_amdgcn_s_setprio(0);
    MEMFENCE; __builtin_amdgcn_s_barrier(); MEMFENCE;
    bfr[2][0] = ldB(bb, 2, 0); bfr[2][1] = ldB(bb, 2, 1);
    if (t + 1 < NT) { stageB(t + 1, 1); stageB(t + 1, 2); }
    if (t + 2 < NT) stageA(t + 2);
    MEMFENCE; __builtin_amdgcn_s_barrier(); MEMFENCE;
    __builtin_amdgcn_s_setprio(1);
#pragma unroll
    for (int mt = 0; mt < 4; ++mt)
#pragma unroll
      for (int ks = 0; ks < 2; ++ks) acc[mt][2] = MFMA16(af[mt][ks], bfr[2][ks], acc[mt][2]);
    __builtin_amdgcn_s_setprio(0);
    if (t + 2 < NT) {
      asm volatile("s_waitcnt vmcnt(2)" ::: "memory");
    } else {
      asm volatile("s_waitcnt vmcnt(0)" ::: "memory");
    }
    __builtin_amdgcn_s_barrier();
    MEMFENCE;
  }

#pragma unroll
  for (int mt = 0; mt < 4; ++mt) {
    int mrow = m0 + wr * 64 + mt * 16 + g4 * 4;
#pragma unroll
    for (int nt = 0; nt < 3; ++nt) {
      int e = wc * 48 + nt * 16 + lo;
      float bv = bias[bx * 192 + e];
#pragma unroll
      for (int r = 0; r < 4; ++r) {
        int mm = mrow + r;
        int b = mm >> 11, n = mm & 2047;
        float v = acc[mt][nt][r] + bv;
        size_t bh64 = (size_t)(b * 16 + bx);
        if (e < 64)       Kout[(bh64 * 2048 + n) * 64 + e] = __float2bfloat16(v);
        else if (e < 128) Qout[(bh64 * 2048 + n) * 64 + e - 64] = __float2bfloat16(v * QSCALE);
        else              Vtout[(bh64 * 64 + (e - 128)) * 2048 + n] = __float2bfloat16(v);
      }
    }
  }
}

// ---------------- proj GEMM v2: 64x128x64 tiles -> 512 blocks, counted vmcnt ----------------
__launch_bounds__(256, 3)
__global__ void gemm_proj_k(const HBF* __restrict__ A, const HBF* __restrict__ Bt,
                            const float* __restrict__ bias, float* __restrict__ Cout) {
  __shared__ __align__(16) HBF As[2][4096];   // 64 x 64
  __shared__ __align__(16) HBF Bs[2][8192];   // 128 x 64
  const int tid = threadIdx.x, lane = tid & 63, w = tid >> 6;
  const int lo = lane & 15, g4 = lane >> 4;
  const int wrp = w >> 1, wcp = w & 1;
  const int s = ((int)blockIdx.x & 7) * 64 + ((int)blockIdx.x >> 3);
  const int bxn = s & 7, by = s >> 3;
  const int m0 = by * 64, n0 = bxn * 128;
  const int NT = 16;  // K=1024 / 64

  f32x4 acc[2][4];
#pragma unroll
  for (int i = 0; i < 2; i++)
#pragma unroll
    for (int j = 0; j < 4; j++) acc[i][j] = (f32x4){0.f, 0.f, 0.f, 0.f};
  bf16x8 af[2][2], bfr[4][2];

  const int rr = tid >> 3;   // 0..31
  const int ch = tid & 7;

  auto stageA = [&](int kt, int h) {
    int row = h * 32 + rr;
    gload_lds16(A + (size_t)(m0 + row) * 1024 + kt * 64 + ((ch ^ (row & 7)) * 8),
                &As[kt & 1][h * 2048] + w * 512);
  };
  auto stageB = [&](int kt, int g) {
    int row = g * 32 + rr;
    gload_lds16(Bt + (size_t)(n0 + row) * 1024 + kt * 64 + ((ch ^ (row & 7)) * 8),
                &Bs[kt & 1][g * 2048] + w * 512);
  };
  auto ldA = [&](int bb, int mt, int ks) -> bf16x8 {
    int row = wrp * 32 + mt * 16 + lo;
    return *reinterpret_cast<const bf16x8*>(&As[bb][row * 64 + ((ks * 32 + g4 * 8) ^ ((row & 7) * 8))]);
  };
  auto ldB = [&](int bb, int nt, int ks) -> bf16x8 {
    int row = wcp * 64 + nt * 16 + lo;
    return *reinterpret_cast<const bf16x8*>(&Bs[bb][row * 64 + ((ks * 32 + g4 * 8) ^ ((row & 7) * 8))]);
  };

  stageA(0, 0); stageA(0, 1);
  stageB(0, 0); stageB(0, 1); stageB(0, 2); stageB(0, 3);
  stageA(1, 0); stageA(1, 1);
  asm volatile("s_waitcnt vmcnt(2)" ::: "memory");
  __builtin_amdgcn_s_barrier();
  MEMFENCE;

  for (int t = 0; t < NT; ++t) {
    const int bb = t & 1;
#pragma unroll
    for (int mt = 0; mt < 2; ++mt) { af[mt][0] = ldA(bb, mt, 0); af[mt][1] = ldA(bb, mt, 1); }
#pragma unroll
    for (int nt = 0; nt < 2; ++nt) { bfr[nt][0] = ldB(bb, nt, 0); bfr[nt][1] = ldB(bb, nt, 1); }
    if (t + 1 < NT) { stageB(t + 1, 0); stageB(t + 1, 1); }
    MEMFENCE; __builtin_amdgcn_s_barrier(); MEMFENCE;
    __builtin_amdgcn_s_setprio(1);
#pragma unroll
    for (int mt = 0; mt < 2; ++mt)
#pragma unroll
      for (int nt = 0; nt < 2; ++nt)
#pragma unroll
        for (int ks = 0; ks < 2; ++ks) acc[mt][nt] = MFMA16(af[mt][ks], bfr[nt][ks], acc[mt][nt]);
    __builtin_amdgcn_s_setprio(0);
    MEMFENCE; __builtin_amdgcn_s_barrier(); MEMFENCE;
#pragma unroll
    for (int nt = 2; nt < 4; ++nt) { bfr[nt][0] = ldB(bb, nt, 0); bfr[nt][1] = ldB(bb, nt, 1); }
    if (t + 1 < NT) { stageB(t + 1, 2); stageB(t + 1, 3); }
    if (t + 2 < NT) { stageA(t + 2, 0); stageA(t + 2, 1); }
    MEMFENCE; __builtin_amdgcn_s_barrier(); MEMFENCE;
    __builtin_amdgcn_s_setprio(1);
#pragma unroll
    for (int mt = 0; mt < 2; ++mt)
#pragma unroll
      for (int nt = 2; nt < 4; ++nt)
#pragma unroll
        for (int ks = 0; ks < 2; ++ks) acc[mt][nt] = MFMA16(af[mt][ks], bfr[nt][ks], acc[mt][nt]);
    __builtin_amdgcn_s_setprio(0);
    if (t + 2 < NT) {
      asm volatile("s_waitcnt vmcnt(2)" ::: "memory");
    } else {
      asm volatile("s_waitcnt vmcnt(0)" ::: "memory");
    }
    __builtin_amdgcn_s_barrier();
    MEMFENCE;
  }

#pragma unroll
  for (int mt = 0; mt < 2; ++mt) {
    int mrow = m0 + wrp * 32 + mt * 16 + g4 * 4;
#pragma unroll
    for (int nt = 0; nt < 4; ++nt) {
      int col = n0 + wcp * 64 + nt * 16 + lo;
      float bv = bias[col];
#pragma unroll
      for (int r = 0; r < 4; ++r)
        Cout[(size_t)(mrow + r) * 1024 + col] = acc[mt][nt][r] + bv;
    }
  }
}

// ---------------- causal flash attention v11: 2 q-tiles/wave, KVBLK=64, 3 blocks/CU ----------------
// grid 512, 256 thr = 4 waves. xcd = lin&7, c = lin>>3, bh = xcd*4 + (c&3), jb = 15-(c>>2)
// (longest-first). Block = 128 q rows [jb*128, +128); wave w owns rows w*32 + qt*16 (qt=0,1) —
// all distinct. K-frags and V-frags loaded once per iter feed both q-tiles. K/V dbuf 32KB +
// pLds[4][2][16x64] 16KB = 48KB -> 3 blocks/CU. Inactive (causal) q-tiles skip compute, keep barrier.
__launch_bounds__(256, 3)
__global__ void attn_fwd_k(const HBF* __restrict__ Qb, const HBF* __restrict__ Kb,
                           const HBF* __restrict__ Vt, HBF* __restrict__ Ob) {
  __shared__ __align__(16) HBF Ks[2][4096];   // [dbuf][64key x 64d]
  __shared__ __align__(16) HBF Vs[2][4096];   // [dbuf][64d x 64key]
  __shared__ __align__(16) HBF pLds[4][2][1024];  // [wave][qt][16q x 64key]
  const int tid = threadIdx.x;
  const int lane = tid & 63;
  const int w = tid >> 6;
  const int lo = lane & 15, g4 = lane >> 4;

  const int lin = blockIdx.x;
  const int xcd = lin & 7, c = lin >> 3;       // c in 0..63
  const int bh = xcd * 4 + (c & 3);            // KV L2-clustered
  const int jb = 15 - (c >> 2);                // longest blocks dispatched first
  const int b = bh >> 4, h = bh & 15;
  const int qw0 = jb * 128 + w * 32;           // qt=0 rows [qw0, qw0+16)
  const int qw1 = qw0 + 16;                    // qt=1 rows
  const int nkv = jb * 2 + 2;                  // 64-key iterations for the block

  const HBF* Qp = Qb + (size_t)bh * 2048 * 64;
  const HBF* Kp = Kb + (size_t)bh * 2048 * 64;
  const HBF* Vp = Vt + (size_t)bh * 64 * 2048;

  bf16x8 qf[2][2];
#pragma unroll
  for (int qt = 0; qt < 2; qt++)
#pragma unroll
    for (int ds = 0; ds < 2; ds++)
      qf[qt][ds] = *reinterpret_cast<const bf16x8*>(
          Qp + (size_t)(qw0 + qt * 16 + lo) * 64 + ds * 32 + g4 * 8);

  const f32x4 zero = {0.f, 0.f, 0.f, 0.f};
  f32x4 o[2][4];
  float m[2] = {-1e30f, -1e30f}, l[2] = {0.f, 0.f};
#pragma unroll
  for (int qt = 0; qt < 2; qt++)
#pragma unroll
    for (int j4 = 0; j4 < 4; j4++) o[qt][j4] = zero;

  const int srow = (lane >> 3) & 7;
  const int sch = lane & 7;
  const int psw = (lo & 7) << 4;  // pLds XOR key (bytes)

  auto stage = [&](int kv0, int sb) {
#pragma unroll
    for (int cc = 0; cc < 2; cc++) {
      int seg = w * 2 + cc;
      int row = seg * 8 + srow;
      gload_lds16(Kp + (size_t)(kv0 + row) * 64 + ((sch ^ (row & 7)) * 8), &Ks[sb][seg * 512]);
      gload_lds16(Vp + (size_t)row * 2048 + kv0 + ((sch ^ (row & 7)) * 8), &Vs[sb][seg * 512]);
    }
  };

  stage(0, 0);
  __syncthreads();

  for (int t = 0; t < nkv; ++t) {
    const int kv0 = t * 64;
    const int sb = t & 1;
    if (t + 1 < nkv) stage(kv0 + 64, sb ^ 1);  // prefetch under compute
    const bool act0 = kv0 <= qw0 + 15;         // qt1 (higher rows) is active whenever qt0 is
    const bool act1 = kv0 <= qw1 + 15;

    // ---- S^T = K · Q^T: K-frags shared across q-tiles ----
    f32x4 st[2][4];
#pragma unroll
    for (int kt = 0; kt < 4; kt++) {
      int krow = kt * 16 + lo;
      bf16x8 kf0 = *reinterpret_cast<const bf16x8*>(&Ks[sb][krow * 64 + ((g4 ^ (krow & 7)) * 8)]);
      bf16x8 kf1 = *reinterpret_cast<const bf16x8*>(&Ks[sb][krow * 64 + (((4 + g4) ^ (krow & 7)) * 8)]);
      if (act1) {
        f32x4 z = zero;
        z = MFMA16(kf0, qf[1][0], z);
        z = MFMA16(kf1, qf[1][1], z);
        st[1][kt] = z;
      }
      if (act0) {
        f32x4 y = zero;
        y = MFMA16(kf0, qf[0][0], y);
        y = MFMA16(kf1, qf[0][1], y);
        st[0][kt] = y;
      }
    }

    // ---- online softmax per q-tile (lane owns q-col = qw + lo) ----
#pragma unroll
    for (int qt = 0; qt < 2; qt++) {
      if (!(qt ? act1 : act0)) continue;
      const int qw = qt ? qw1 : qw0;
      const int q = qw + lo;
      float pmax = -1e30f;
      if (kv0 + 63 > qw) {  // mask needed
#pragma unroll
        for (int kt = 0; kt < 4; kt++)
#pragma unroll
          for (int r = 0; r < 4; r++) {
            int key = kv0 + kt * 16 + g4 * 4 + r;
            float v = (key <= q) ? st[qt][kt][r] : -1e30f;
            st[qt][kt][r] = v;
            pmax = fmaxf(pmax, v);
          }
      } else {
#pragma unroll
        for (int kt = 0; kt < 4; kt++)
#pragma unroll
          for (int r = 0; r < 4; r++) pmax = fmaxf(pmax, st[qt][kt][r]);
      }
      pmax = fmaxf(pmax, __shfl_xor(pmax, 16));
      pmax = fmaxf(pmax, __shfl_xor(pmax, 32));
      if (__any(pmax > m[qt] + 11.5f)) {  // defer-max
        float mn = fmaxf(m[qt], pmax);
        float al = EXP2F(m[qt] - mn);
        m[qt] = mn;
        l[qt] *= al;
        float alr[4];
#pragma unroll
        for (int r = 0; r < 4; r++) alr[r] = __shfl(al, g4 * 4 + r);
#pragma unroll
        for (int j4 = 0; j4 < 4; j4++)
#pragma unroll
          for (int r = 0; r < 4; r++) o[qt][j4][r] *= alr[r];
      }
#pragma unroll
      for (int kt = 0; kt < 4; kt++)
#pragma unroll
        for (int r = 0; r < 4; r++) {
          float p = EXP2F(st[qt][kt][r] - m[qt]);
          st[qt][kt][r] = p;
          l[qt] += p;  // lane-partial; reduced in epilogue
        }
#pragma unroll
      for (int kt = 0; kt < 4; kt++) {
        bf16x4 pk;
#pragma unroll
        for (int r = 0; r < 4; r++) pk[r] = (__bf16)st[qt][kt][r];
        *reinterpret_cast<bf16x4*>(
            &pLds[w][qt][lo * 64 + (((kt * 32 + g4 * 8) ^ psw) >> 1)]) = pk;
      }
    }
    asm volatile("s_waitcnt lgkmcnt(0)" ::: "memory");
    __builtin_amdgcn_sched_barrier(0);

    // ---- PV: V-frags shared across q-tiles ----
    bf16x8 pa0[2], pa1[2];
#pragma unroll
    for (int ks = 0; ks < 2; ks++) {
      if (act1) pa1[ks] = *reinterpret_cast<const bf16x8*>(
          &pLds[w][1][lo * 64 + (((ks * 64 + g4 * 16) ^ psw) >> 1)]);
      if (act0) pa0[ks] = *reinterpret_cast<const bf16x8*>(
          &pLds[w][0][lo * 64 + (((ks * 64 + g4 * 16) ^ psw) >> 1)]);
    }
#pragma unroll
    for (int j4 = 0; j4 < 4; j4++) {
      int vrow = j4 * 16 + lo;
#pragma unroll
      for (int ks = 0; ks < 2; ks++) {
        bf16x8 vb = *reinterpret_cast<const bf16x8*>(
            &Vs[sb][vrow * 64 + (((ks * 4 + g4) ^ (vrow & 7)) * 8)]);
        if (act1) o[1][j4] = MFMA16(pa1[ks], vb, o[1][j4]);
        if (act0) o[0][j4] = MFMA16(pa0[ks], vb, o[0][j4]);
      }
    }
    __syncthreads();  // drains prefetch + protects LDS reuse
  }

  // ---- epilogue: both q-tiles ----
#pragma unroll
  for (int qt = 0; qt < 2; qt++) {
    float lv = l[qt];
    lv += __shfl_xor(lv, 16);
    lv += __shfl_xor(lv, 32);
    float linv = 1.f / lv;
    float lr[4];
#pragma unroll
    for (int r = 0; r < 4; r++) lr[r] = __shfl(linv, g4 * 4 + r);
    const int qw = qt ? qw1 : qw0;
#pragma unroll
    for (int j4 = 0; j4 < 4; j4++)
#pragma unroll
      for (int r = 0; r < 4; r++) {
        int q = qw + g4 * 4 + r;
        Ob[(size_t)(b * 2048 + q) * 1024 + h * 64 + j4 * 16 + lo] =
            __float2bfloat16(o[qt][j4][r] * lr[r]);
      }
  }
}

// ---------------- launch ----------------
extern "C" void kernel_launch(void* const* d_in, const int* in_sizes, int n_in,
                              void* d_out, int out_size, void* d_ws, size_t ws_size,
                              hipStream_t stream) {
  const float* x      = (const float*)d_in[0];
  const float* W_qkv  = (const float*)d_in[1];
  const float* b_qkv  = (const float*)d_in[2];
  const float* W_proj = (const float*)d_in[3];
  const float* b_proj = (const float*)d_in[4];
  float* out = (float*)d_out;

  const int B = 2, N = 2048, D = 1024, H = 16, DH = 64;
  const int M = B * N;  // 4096

  char* ws = (char*)d_ws;
  HBF* xb      = (HBF*)ws; ws += (size_t)M * D * 2;
  HBF* wqkv_t  = (HBF*)ws; ws += (size_t)H * 3 * DH * D * 2;
  HBF* wproj_t = (HBF*)ws; ws += (size_t)D * D * 2;
  HBF* Qb      = (HBF*)ws; ws += (size_t)B * H * N * DH * 2;
  HBF* Kb      = (HBF*)ws; ws += (size_t)B * H * N * DH * 2;
  HBF* Vt      = (HBF*)ws; ws += (size_t)B * H * DH * N * 2;
  HBF* Ob      = (HBF*)ws; ws += (size_t)M * D * 2;

  prep_k<<<8192, 256, 0, stream>>>(x, xb, W_qkv, wqkv_t, W_proj, wproj_t);
  gemm_qkv_8ph<<<512, 512, 0, stream>>>(xb, wqkv_t, b_qkv, Kb, Qb, Vt);
  attn_fwd_k<<<512, 256, 0, stream>>>(Qb, Kb, Vt, Ob);
  gemm_proj_k<<<512, 256, 0, stream>>>(Ob, wproj_t, b_proj, out);
}

// Round 21
// 97.383 us; speedup vs baseline: 1.2907x; 1.2907x over previous
//
#include <hip/hip_runtime.h>
#include <hip/hip_bf16.h>

typedef __hip_bfloat16 HBF;
typedef __bf16 bf16x8 __attribute__((ext_vector_type(8)));
typedef __bf16 bf16x4 __attribute__((ext_vector_type(4)));
typedef float f32x4 __attribute__((ext_vector_type(4)));
typedef float float4v __attribute__((ext_vector_type(4)));

__device__ __forceinline__ float toF(float x) { return x; }
__device__ __forceinline__ float toF(HBF x) { return __bfloat162float(x); }

#define MFMA16(a, b, c) __builtin_amdgcn_mfma_f32_16x16x32_bf16((a), (b), (c), 0, 0, 0)
#define EXP2F(x) __builtin_amdgcn_exp2f(x)
#define QSCALE 0.18033688011112042f
#define MEMFENCE asm volatile("" ::: "memory")

// async global->LDS, 16B per lane. LDS dest must be wave-uniform base; HW adds lane*16.
__device__ __forceinline__ void gload_lds16(const HBF* g, HBF* l) {
  __builtin_amdgcn_global_load_lds((const __attribute__((address_space(1))) void*)g,
                                   (__attribute__((address_space(3))) void*)l, 16, 0, 0);
}

// ---------------- fused prep: x cast + W_qkv transpose + W_proj transpose ----------------
__global__ void prep_k(const float* __restrict__ x, HBF* __restrict__ xb,
                       const float* __restrict__ Wqkv, HBF* __restrict__ wqkv_t,
                       const float* __restrict__ Wproj, HBF* __restrict__ wproj_t) {
  const int bid = blockIdx.x, tid = threadIdx.x;
  if (bid < 4096) {
    int i = bid * 256 + tid;
    float4v a = reinterpret_cast<const float4v*>(x)[i];
    HBF o[4] = {__float2bfloat16(a.x), __float2bfloat16(a.y),
                __float2bfloat16(a.z), __float2bfloat16(a.w)};
    *reinterpret_cast<ulonglong1*>(&xb[i * 4]) = *reinterpret_cast<ulonglong1*>(o);
    return;
  }
  __shared__ float tile[32][33];
  const float* in;
  HBF* out;
  int R, C, gx, gy;
  size_t base;
  if (bid < 7168) {  // W_qkv (16,1024,192) -> (16,192,1024)
    int t = bid - 4096;
    int gz = t / 192, rem = t % 192;
    gy = rem / 6; gx = rem % 6;
    R = 1024; C = 192;
    base = (size_t)gz * R * C;
    in = Wqkv; out = wqkv_t;
  } else {           // W_proj (1024,1024) -> transposed
    int t = bid - 7168;
    gy = t / 32; gx = t % 32;
    R = 1024; C = 1024;
    base = 0;
    in = Wproj; out = wproj_t;
  }
  int r0 = gy * 32, c0 = gx * 32;
  int tx = tid & 31, ty = tid >> 5;
#pragma unroll
  for (int i = ty; i < 32; i += 8)
    tile[i][tx] = in[base + (size_t)(r0 + i) * C + c0 + tx];
  __syncthreads();
#pragma unroll
  for (int i = ty; i < 32; i += 8)
    out[base + (size_t)(c0 + i) * R + r0 + tx] = __float2bfloat16(tile[tx][i]);
}

// ---------------- QKV GEMM v3: 128x192x64 tiles -> 512 blocks (2/CU), counted vmcnt ----------------
__launch_bounds__(512, 4)
__global__ void gemm_qkv_8ph(const HBF* __restrict__ A, const HBF* __restrict__ Bt,
                             const float* __restrict__ bias,
                             HBF* __restrict__ Kout, HBF* __restrict__ Qout,
                             HBF* __restrict__ Vtout) {
  __shared__ __align__(16) HBF As[2][8192];
  __shared__ __align__(16) HBF Bs[2][12288];
  const int tid = threadIdx.x, lane = tid & 63, w = tid >> 6;
  const int lo = lane & 15, g4 = lane >> 4;
  const int wr = w >> 2, wc = w & 3;
  const int s = ((int)blockIdx.x & 7) * 64 + ((int)blockIdx.x >> 3);
  const int bx = s & 15, by = s >> 4;
  const int m0 = by * 128, n0 = bx * 192;  // bx == head
  const int NT = 16;  // K=1024 / 64

  f32x4 acc[4][3];
#pragma unroll
  for (int i = 0; i < 4; i++)
#pragma unroll
    for (int j = 0; j < 3; j++) acc[i][j] = (f32x4){0.f, 0.f, 0.f, 0.f};
  bf16x8 af[4][2], bfr[3][2];

  const int rl0 = w * 8 + (lane >> 3);
  const int rl1 = 64 + rl0;
  const int kc0 = (lane & 7) ^ (rl0 & 7);
  const int kc1 = (lane & 7) ^ (rl1 & 7);

  auto stageA = [&](int kt) {
    HBF* base = &As[kt & 1][0];
    gload_lds16(A + (size_t)(m0 + rl0) * 1024 + kt * 64 + kc0 * 8, base + w * 512);
    gload_lds16(A + (size_t)(m0 + rl1) * 1024 + kt * 64 + kc1 * 8, base + 4096 + w * 512);
  };
  auto stageB = [&](int kt, int g) {
    gload_lds16(Bt + (size_t)(n0 + g * 64 + rl0) * 1024 + kt * 64 + kc0 * 8,
                &Bs[kt & 1][g * 4096] + w * 512);
  };
  auto ldA = [&](int bb, int mt, int ks) -> bf16x8 {
    int row = wr * 64 + mt * 16 + lo;
    return *reinterpret_cast<const bf16x8*>(&As[bb][row * 64 + ((ks * 32 + g4 * 8) ^ ((row & 7) * 8))]);
  };
  auto ldB = [&](int bb, int nt, int ks) -> bf16x8 {
    int row = wc * 48 + nt * 16 + lo;
    return *reinterpret_cast<const bf16x8*>(&Bs[bb][row * 64 + ((ks * 32 + g4 * 8) ^ ((row & 7) * 8))]);
  };

  stageA(0); stageB(0, 0); stageB(0, 1); stageB(0, 2);
  stageA(1);
  asm volatile("s_waitcnt vmcnt(2)" ::: "memory");
  __builtin_amdgcn_s_barrier();
  MEMFENCE;

  for (int t = 0; t < NT; ++t) {
    const int bb = t & 1;
#pragma unroll
    for (int mt = 0; mt < 4; ++mt) { af[mt][0] = ldA(bb, mt, 0); af[mt][1] = ldA(bb, mt, 1); }
#pragma unroll
    for (int nt = 0; nt < 2; ++nt) { bfr[nt][0] = ldB(bb, nt, 0); bfr[nt][1] = ldB(bb, nt, 1); }
    if (t + 1 < NT) stageB(t + 1, 0);
    MEMFENCE; __builtin_amdgcn_s_barrier(); MEMFENCE;
    __builtin_amdgcn_s_setprio(1);
#pragma unroll
    for (int mt = 0; mt < 4; ++mt)
#pragma unroll
      for (int nt = 0; nt < 2; ++nt)
#pragma unroll
        for (int ks = 0; ks < 2; ++ks) acc[mt][nt] = MFMA16(af[mt][ks], bfr[nt][ks], acc[mt][nt]);
    __builtin_amdgcn_s_setprio(0);
    MEMFENCE; __builtin_amdgcn_s_barrier(); MEMFENCE;
    bfr[2][0] = ldB(bb, 2, 0); bfr[2][1] = ldB(bb, 2, 1);
    if (t + 1 < NT) { stageB(t + 1, 1); stageB(t + 1, 2); }
    if (t + 2 < NT) stageA(t + 2);
    MEMFENCE; __builtin_amdgcn_s_barrier(); MEMFENCE;
    __builtin_amdgcn_s_setprio(1);
#pragma unroll
    for (int mt = 0; mt < 4; ++mt)
#pragma unroll
      for (int ks = 0; ks < 2; ++ks) acc[mt][2] = MFMA16(af[mt][ks], bfr[2][ks], acc[mt][2]);
    __builtin_amdgcn_s_setprio(0);
    if (t + 2 < NT) {
      asm volatile("s_waitcnt vmcnt(2)" ::: "memory");
    } else {
      asm volatile("s_waitcnt vmcnt(0)" ::: "memory");
    }
    __builtin_amdgcn_s_barrier();
    MEMFENCE;
  }

#pragma unroll
  for (int mt = 0; mt < 4; ++mt) {
    int mrow = m0 + wr * 64 + mt * 16 + g4 * 4;
#pragma unroll
    for (int nt = 0; nt < 3; ++nt) {
      int e = wc * 48 + nt * 16 + lo;
      float bv = bias[bx * 192 + e];
#pragma unroll
      for (int r = 0; r < 4; ++r) {
        int mm = mrow + r;
        int b = mm >> 11, n = mm & 2047;
        float v = acc[mt][nt][r] + bv;
        size_t bh64 = (size_t)(b * 16 + bx);
        if (e < 64)       Kout[(bh64 * 2048 + n) * 64 + e] = __float2bfloat16(v);
        else if (e < 128) Qout[(bh64 * 2048 + n) * 64 + e - 64] = __float2bfloat16(v * QSCALE);
        else              Vtout[(bh64 * 64 + (e - 128)) * 2048 + n] = __float2bfloat16(v);
      }
    }
  }
}

// ---------------- proj GEMM v2: 64x128x64 tiles -> 512 blocks, counted vmcnt ----------------
__launch_bounds__(256, 3)
__global__ void gemm_proj_k(const HBF* __restrict__ A, const HBF* __restrict__ Bt,
                            const float* __restrict__ bias, float* __restrict__ Cout) {
  __shared__ __align__(16) HBF As[2][4096];   // 64 x 64
  __shared__ __align__(16) HBF Bs[2][8192];   // 128 x 64
  const int tid = threadIdx.x, lane = tid & 63, w = tid >> 6;
  const int lo = lane & 15, g4 = lane >> 4;
  const int wrp = w >> 1, wcp = w & 1;
  const int s = ((int)blockIdx.x & 7) * 64 + ((int)blockIdx.x >> 3);
  const int bxn = s & 7, by = s >> 3;
  const int m0 = by * 64, n0 = bxn * 128;
  const int NT = 16;  // K=1024 / 64

  f32x4 acc[2][4];
#pragma unroll
  for (int i = 0; i < 2; i++)
#pragma unroll
    for (int j = 0; j < 4; j++) acc[i][j] = (f32x4){0.f, 0.f, 0.f, 0.f};
  bf16x8 af[2][2], bfr[4][2];

  const int rr = tid >> 3;   // 0..31
  const int ch = tid & 7;

  auto stageA = [&](int kt, int h) {
    int row = h * 32 + rr;
    gload_lds16(A + (size_t)(m0 + row) * 1024 + kt * 64 + ((ch ^ (row & 7)) * 8),
                &As[kt & 1][h * 2048] + w * 512);
  };
  auto stageB = [&](int kt, int g) {
    int row = g * 32 + rr;
    gload_lds16(Bt + (size_t)(n0 + row) * 1024 + kt * 64 + ((ch ^ (row & 7)) * 8),
                &Bs[kt & 1][g * 2048] + w * 512);
  };
  auto ldA = [&](int bb, int mt, int ks) -> bf16x8 {
    int row = wrp * 32 + mt * 16 + lo;
    return *reinterpret_cast<const bf16x8*>(&As[bb][row * 64 + ((ks * 32 + g4 * 8) ^ ((row & 7) * 8))]);
  };
  auto ldB = [&](int bb, int nt, int ks) -> bf16x8 {
    int row = wcp * 64 + nt * 16 + lo;
    return *reinterpret_cast<const bf16x8*>(&Bs[bb][row * 64 + ((ks * 32 + g4 * 8) ^ ((row & 7) * 8))]);
  };

  stageA(0, 0); stageA(0, 1);
  stageB(0, 0); stageB(0, 1); stageB(0, 2); stageB(0, 3);
  stageA(1, 0); stageA(1, 1);
  asm volatile("s_waitcnt vmcnt(2)" ::: "memory");
  __builtin_amdgcn_s_barrier();
  MEMFENCE;

  for (int t = 0; t < NT; ++t) {
    const int bb = t & 1;
#pragma unroll
    for (int mt = 0; mt < 2; ++mt) { af[mt][0] = ldA(bb, mt, 0); af[mt][1] = ldA(bb, mt, 1); }
#pragma unroll
    for (int nt = 0; nt < 2; ++nt) { bfr[nt][0] = ldB(bb, nt, 0); bfr[nt][1] = ldB(bb, nt, 1); }
    if (t + 1 < NT) { stageB(t + 1, 0); stageB(t + 1, 1); }
    MEMFENCE; __builtin_amdgcn_s_barrier(); MEMFENCE;
    __builtin_amdgcn_s_setprio(1);
#pragma unroll
    for (int mt = 0; mt < 2; ++mt)
#pragma unroll
      for (int nt = 0; nt < 2; ++nt)
#pragma unroll
        for (int ks = 0; ks < 2; ++ks) acc[mt][nt] = MFMA16(af[mt][ks], bfr[nt][ks], acc[mt][nt]);
    __builtin_amdgcn_s_setprio(0);
    MEMFENCE; __builtin_amdgcn_s_barrier(); MEMFENCE;
#pragma unroll
    for (int nt = 2; nt < 4; ++nt) { bfr[nt][0] = ldB(bb, nt, 0); bfr[nt][1] = ldB(bb, nt, 1); }
    if (t + 1 < NT) { stageB(t + 1, 2); stageB(t + 1, 3); }
    if (t + 2 < NT) { stageA(t + 2, 0); stageA(t + 2, 1); }
    MEMFENCE; __builtin_amdgcn_s_barrier(); MEMFENCE;
    __builtin_amdgcn_s_setprio(1);
#pragma unroll
    for (int mt = 0; mt < 2; ++mt)
#pragma unroll
      for (int nt = 2; nt < 4; ++nt)
#pragma unroll
        for (int ks = 0; ks < 2; ++ks) acc[mt][nt] = MFMA16(af[mt][ks], bfr[nt][ks], acc[mt][nt]);
    __builtin_amdgcn_s_setprio(0);
    if (t + 2 < NT) {
      asm volatile("s_waitcnt vmcnt(2)" ::: "memory");
    } else {
      asm volatile("s_waitcnt vmcnt(0)" ::: "memory");
    }
    __builtin_amdgcn_s_barrier();
    MEMFENCE;
  }

#pragma unroll
  for (int mt = 0; mt < 2; ++mt) {
    int mrow = m0 + wrp * 32 + mt * 16 + g4 * 4;
#pragma unroll
    for (int nt = 0; nt < 4; ++nt) {
      int col = n0 + wcp * 64 + nt * 16 + lo;
      float bv = bias[col];
#pragma unroll
      for (int r = 0; r < 4; ++r)
        Cout[(size_t)(mrow + r) * 1024 + col] = acc[mt][nt][r] + bv;
    }
  }
}

// ---------------- causal flash attention v9 (best, R13/R15): KVBLK=128, double-buffered ----------------
__launch_bounds__(256, 2)
__global__ void attn_fwd_k(const HBF* __restrict__ Qb, const HBF* __restrict__ Kb,
                           const HBF* __restrict__ Vt, HBF* __restrict__ Ob) {
  __shared__ __align__(16) HBF Ks[2][2][4096];  // [dbuf][sub][64key x 64d]
  __shared__ __align__(16) HBF Vs[2][2][4096];  // [dbuf][sub][64d x 64key]
  __shared__ __align__(16) HBF pLds[4][2048];   // wave-local 16 q x 128 key
  const int tid = threadIdx.x;
  const int lane = tid & 63;
  const int w = tid >> 6;
  const int lo = lane & 15, g4 = lane >> 4;

  const int lin = blockIdx.x;
  const int xcd = lin & 7, c = lin >> 3;       // c in 0..127
  const int bh = xcd * 4 + (c & 3);            // 4 (b,h) per XCD -> KV L2-clustered
  const int j = 31 - (c >> 2);                 // longest tiles dispatched first
  const int b = bh >> 4, h = bh & 15;
  const int qrow0 = j * 64 + w * 16;
  const int nkv = (j + 2) >> 1;                // 128-key iterations

  const HBF* Qp = Qb + (size_t)bh * 2048 * 64;
  const HBF* Kp = Kb + (size_t)bh * 2048 * 64;
  const HBF* Vp = Vt + (size_t)bh * 64 * 2048;

  bf16x8 qf[2];
#pragma unroll
  for (int ds = 0; ds < 2; ds++)
    qf[ds] = *reinterpret_cast<const bf16x8*>(Qp + (size_t)(qrow0 + lo) * 64 + ds * 32 + g4 * 8);

  const f32x4 zero = {0.f, 0.f, 0.f, 0.f};
  f32x4 o[4];
  float m = -1e30f, l = 0.f;
#pragma unroll
  for (int j4 = 0; j4 < 4; j4++) o[j4] = zero;

  const int srow = (lane >> 3) & 7;
  const int sch = lane & 7;
  const int psw = (lo & 7) << 4;  // pLds XOR key (bytes)

  auto stage = [&](int kv0, int sb) {  // kv0 = 128-aligned
#pragma unroll
    for (int sub = 0; sub < 2; sub++)
#pragma unroll
      for (int cc = 0; cc < 2; cc++) {
        int seg = w * 2 + cc;
        int row = seg * 8 + srow;
        gload_lds16(Kp + (size_t)(kv0 + sub * 64 + row) * 64 + ((sch ^ (row & 7)) * 8),
                    &Ks[sb][sub][seg * 512]);
        gload_lds16(Vp + (size_t)row * 2048 + kv0 + sub * 64 + ((sch ^ (row & 7)) * 8),
                    &Vs[sb][sub][seg * 512]);
      }
  };

  stage(0, 0);
  __syncthreads();

  for (int t = 0; t < nkv; ++t) {
    const int kv0 = t * 128;
    const int sb = t & 1;
    if (t + 1 < nkv) stage(kv0 + 128, sb ^ 1);  // prefetch under compute

    // ---- S^T = K · Q^T over 128 keys (2 subs x 4 kt) ----
    f32x4 st[2][4];
#pragma unroll
    for (int sub = 0; sub < 2; sub++)
#pragma unroll
      for (int kt = 0; kt < 4; kt++) {
        int krow = kt * 16 + lo;
        bf16x8 kf0 = *reinterpret_cast<const bf16x8*>(&Ks[sb][sub][krow * 64 + ((g4 ^ (krow & 7)) * 8)]);
        bf16x8 kf1 = *reinterpret_cast<const bf16x8*>(&Ks[sb][sub][krow * 64 + (((4 + g4) ^ (krow & 7)) * 8)]);
        f32x4 z = zero;
        z = MFMA16(kf0, qf[0], z);
        z = MFMA16(kf1, qf[1], z);
        st[sub][kt] = z;
      }

    // ---- online softmax (lane owns q-col = qrow0 + lo) ----
    const int q = qrow0 + lo;
    float pmax = -1e30f;
    if (t == nkv - 1) {  // diagonal iter: mask
#pragma unroll
      for (int sub = 0; sub < 2; sub++)
#pragma unroll
        for (int kt = 0; kt < 4; kt++)
#pragma unroll
          for (int r = 0; r < 4; r++) {
            int key = kv0 + sub * 64 + kt * 16 + g4 * 4 + r;
            float v = (key <= q) ? st[sub][kt][r] : -1e30f;
            st[sub][kt][r] = v;
            pmax = fmaxf(pmax, v);
          }
    } else {
#pragma unroll
      for (int sub = 0; sub < 2; sub++)
#pragma unroll
        for (int kt = 0; kt < 4; kt++)
#pragma unroll
          for (int r = 0; r < 4; r++) pmax = fmaxf(pmax, st[sub][kt][r]);
    }
    pmax = fmaxf(pmax, __shfl_xor(pmax, 16));
    pmax = fmaxf(pmax, __shfl_xor(pmax, 32));
    if (__any(pmax > m + 11.5f)) {  // defer-max
      float mn = fmaxf(m, pmax);
      float al = EXP2F(m - mn);
      m = mn;
      l *= al;
      float alr[4];
#pragma unroll
      for (int r = 0; r < 4; r++) alr[r] = __shfl(al, g4 * 4 + r);
#pragma unroll
      for (int j4 = 0; j4 < 4; j4++)
#pragma unroll
        for (int r = 0; r < 4; r++) o[j4][r] *= alr[r];
    }
#pragma unroll
    for (int sub = 0; sub < 2; sub++)
#pragma unroll
      for (int kt = 0; kt < 4; kt++)
#pragma unroll
        for (int r = 0; r < 4; r++) {
          float p = EXP2F(st[sub][kt][r] - m);
          st[sub][kt][r] = p;
          l += p;  // lane-partial; reduced in epilogue
        }
    // pack P -> swizzled pLds
#pragma unroll
    for (int sub = 0; sub < 2; sub++)
#pragma unroll
      for (int kt = 0; kt < 4; kt++) {
        bf16x4 pk;
#pragma unroll
        for (int r = 0; r < 4; r++) pk[r] = (__bf16)st[sub][kt][r];
        *reinterpret_cast<bf16x4*>(
            &pLds[w][lo * 128 + (((sub * 128 + kt * 32 + g4 * 8) ^ psw) >> 1)]) = pk;
      }
    asm volatile("s_waitcnt lgkmcnt(0)" ::: "memory");
    __builtin_amdgcn_sched_barrier(0);

    // ---- PV: 4 ks-groups of 32 keys ----
    bf16x8 pa[4];
#pragma unroll
    for (int ks = 0; ks < 4; ks++)
      pa[ks] = *reinterpret_cast<const bf16x8*>(
          &pLds[w][lo * 128 + (((ks * 64 + g4 * 16) ^ psw) >> 1)]);
#pragma unroll
    for (int j4 = 0; j4 < 4; j4++) {
      int vrow = j4 * 16 + lo;
#pragma unroll
      for (int ks = 0; ks < 4; ks++) {
        bf16x8 vb = *reinterpret_cast<const bf16x8*>(
            &Vs[sb][ks >> 1][vrow * 64 + ((((ks & 1) * 4 + g4) ^ (vrow & 7)) * 8)]);
        o[j4] = MFMA16(pa[ks], vb, o[j4]);
      }
    }
    __syncthreads();  // drains prefetch + protects LDS reuse
  }

  // ---- epilogue ----
  l += __shfl_xor(l, 16);
  l += __shfl_xor(l, 32);
  float linv = 1.f / l;
  float lr[4];
#pragma unroll
  for (int r = 0; r < 4; r++) lr[r] = __shfl(linv, g4 * 4 + r);
#pragma unroll
  for (int j4 = 0; j4 < 4; j4++)
#pragma unroll
    for (int r = 0; r < 4; r++) {
      int q = qrow0 + g4 * 4 + r;
      Ob[(size_t)(b * 2048 + q) * 1024 + h * 64 + j4 * 16 + lo] =
          __float2bfloat16(o[j4][r] * lr[r]);
    }
}

// ---------------- launch ----------------
extern "C" void kernel_launch(void* const* d_in, const int* in_sizes, int n_in,
                              void* d_out, int out_size, void* d_ws, size_t ws_size,
                              hipStream_t stream) {
  const float* x      = (const float*)d_in[0];
  const float* W_qkv  = (const float*)d_in[1];
  const float* b_qkv  = (const float*)d_in[2];
  const float* W_proj = (const float*)d_in[3];
  const float* b_proj = (const float*)d_in[4];
  float* out = (float*)d_out;

  const int B = 2, N = 2048, D = 1024, H = 16, DH = 64;
  const int M = B * N;  // 4096

  char* ws = (char*)d_ws;
  HBF* xb      = (HBF*)ws; ws += (size_t)M * D * 2;
  HBF* wqkv_t  = (HBF*)ws; ws += (size_t)H * 3 * DH * D * 2;
  HBF* wproj_t = (HBF*)ws; ws += (size_t)D * D * 2;
  HBF* Qb      = (HBF*)ws; ws += (size_t)B * H * N * DH * 2;
  HBF* Kb      = (HBF*)ws; ws += (size_t)B * H * N * DH * 2;
  HBF* Vt      = (HBF*)ws; ws += (size_t)B * H * DH * N * 2;
  HBF* Ob      = (HBF*)ws; ws += (size_t)M * D * 2;

  prep_k<<<8192, 256, 0, stream>>>(x, xb, W_qkv, wqkv_t, W_proj, wproj_t);
  gemm_qkv_8ph<<<512, 512, 0, stream>>>(xb, wqkv_t, b_qkv, Kb, Qb, Vt);
  attn_fwd_k<<<1024, 256, 0, stream>>>(Qb, Kb, Vt, Ob);
  gemm_proj_k<<<512, 256, 0, stream>>>(Ob, wproj_t, b_proj, out);
}